// Round 11
// baseline (374.356 us; speedup 1.0000x reference)
//
#include <hip/hip_runtime.h>
#include <stdint.h>

// ===================== problem constants =====================
constexpr int D_MODEL = 768;
constexpr int SEQ     = 4096;
constexpr int NHEAD   = 12;
constexpr int HDIM    = 64;
constexpr int BATCH   = 2;
constexpr int DFF     = 3072;
constexpr int ROWS    = BATCH * SEQ;   // 8192

typedef __attribute__((ext_vector_type(8))) __bf16 bfrag;
typedef __attribute__((ext_vector_type(8))) short  s16x8;
typedef __attribute__((ext_vector_type(4))) short  s16x4;
typedef __attribute__((ext_vector_type(4))) float  f32x4;

#define MFMA16(a, b, c) __builtin_amdgcn_mfma_f32_16x16x32_bf16((a), (b), (c), 0, 0, 0)
#define AS1(p) ((__attribute__((address_space(1))) void*)(uintptr_t)(p))
#define AS3(p) ((__attribute__((address_space(3))) void*)(p))

__device__ __forceinline__ float b2f(short s) {
  union { unsigned u; float f; } c;
  c.u = ((unsigned)(unsigned short)s) << 16;
  return c.f;
}
__device__ __forceinline__ short f2b(float f) {
  union { float f; unsigned u; } c;
  c.f = f;
  unsigned r = c.u + 0x7fffu + ((c.u >> 16) & 1u);  // RNE (finite inputs only)
  return (short)(r >> 16);
}

// ===================== static BigBird plan (constexpr MT19937 == np.random.RandomState(0)) =====================
struct PlanT { int v[64][8]; };

struct MTRng {
  unsigned mt[624];
  int mti;
  constexpr MTRng() : mt{}, mti(624) {
    mt[0] = 0u;
    for (int i = 1; i < 624; ++i)
      mt[i] = 1812433253u * (mt[i-1] ^ (mt[i-1] >> 30)) + (unsigned)i;
  }
  constexpr unsigned next() {
    if (mti >= 624) {
      for (int i = 0; i < 624; ++i) {
        unsigned y = (mt[i] & 0x80000000u) | (mt[(i+1) % 624] & 0x7fffffffu);
        unsigned v = mt[(i+397) % 624] ^ (y >> 1);
        if (y & 1u) v ^= 0x9908b0dfu;
        mt[i] = v;
      }
      mti = 0;
    }
    unsigned y = mt[mti++];
    y ^= y >> 11;
    y ^= (y << 7)  & 0x9d2c5680u;
    y ^= (y << 15) & 0xefc60000u;
    y ^= y >> 18;
    return y;
  }
  constexpr unsigned interval(unsigned mx) {
    unsigned mask = mx;
    mask |= mask >> 1; mask |= mask >> 2; mask |= mask >> 4;
    mask |= mask >> 8; mask |= mask >> 16;
    unsigned v = next() & mask;
    while (v > mx) v = next() & mask;
    return v;
  }
};

constexpr PlanT make_plan() {
  PlanT P{};
  MTRng rng{};
  for (int i = 1; i <= 62; ++i) {
    int cand[64] = {}; int n = 0;
    for (int j = 0; j < 64; ++j) {
      if (j == 0 || j == 63 || j == i-1 || j == i || j == i+1) continue;
      cand[n++] = j;
    }
    int perm[64] = {};
    for (int p = 0; p < n; ++p) perm[p] = p;
    for (int p = n - 1; p > 0; --p) {
      int j = (int)rng.interval((unsigned)p);
      int t = perm[p]; perm[p] = perm[j]; perm[j] = t;
    }
    P.v[i][0] = 0;  P.v[i][1] = 63; P.v[i][2] = i-1; P.v[i][3] = i; P.v[i][4] = i+1;
    P.v[i][5] = cand[perm[0]]; P.v[i][6] = cand[perm[1]]; P.v[i][7] = cand[perm[2]];
  }
  return P;
}
constexpr PlanT h_plan = make_plan();
__constant__ PlanT g_plan = h_plan;

// ===================== layernorm (fp32 in, bf16 out) =====================
__global__ __launch_bounds__(256) void ln_kernel(
    const float* __restrict__ x, const float* __restrict__ sc,
    const float* __restrict__ bi, short* __restrict__ y)
{
  const int row = blockIdx.x, tid = threadIdx.x;
  const size_t base = (size_t)row * D_MODEL;
  float v0 = x[base + tid], v1 = x[base + tid + 256], v2 = x[base + tid + 512];
  float s  = v0 + v1 + v2;
  float s2 = v0*v0 + v1*v1 + v2*v2;
  for (int off = 1; off < 64; off <<= 1) {
    s  += __shfl_xor(s,  off);
    s2 += __shfl_xor(s2, off);
  }
  __shared__ float red[8];
  if ((tid & 63) == 0) { red[tid >> 6] = s; red[4 + (tid >> 6)] = s2; }
  __syncthreads();
  s  = red[0] + red[1] + red[2] + red[3];
  s2 = red[4] + red[5] + red[6] + red[7];
  const float mu  = s * (1.f / 768.f);
  const float var = s2 * (1.f / 768.f) - mu * mu;
  const float rs  = rsqrtf(var + 1e-6f);
  short* yr = y + base;
  yr[tid]       = f2b((v0 - mu) * rs * sc[tid]       + bi[tid]);
  yr[tid + 256] = f2b((v1 - mu) * rs * sc[tid + 256] + bi[tid + 256]);
  yr[tid + 512] = f2b((v2 - mu) * rs * sc[tid + 512] + bi[tid + 512]);
}

// ===================== fused weight transposes (fp32 R x C -> bf16 C x R), 1 dispatch =====================
struct TrArgs { const float* src[6]; short* dst[6]; };

__global__ __launch_bounds__(256) void tr_all(TrArgs a) {
  __shared__ short tile[32][33];
  const int idx = blockIdx.x;
  int w, bx, by, Rr, Cc;
  if (idx < 2304)      { w = idx / 576; int t = idx % 576;  bx = t % 24; by = t / 24; Rr = 768;  Cc = 768;  }
  else if (idx < 4608) { w = 4;         int t = idx - 2304; bx = t % 96; by = t / 96; Rr = 768;  Cc = 3072; }
  else                 { w = 5;         int t = idx - 4608; bx = t % 24; by = t / 24; Rr = 3072; Cc = 768;  }
  const float* in = a.src[w];
  short* out = a.dst[w];
  const int x0 = bx * 32, y0 = by * 32;
  const int tx = threadIdx.x & 31, ty = threadIdx.x >> 5;
  for (int i = 0; i < 32; i += 8)
    tile[ty + i][tx] = f2b(in[(size_t)(y0 + ty + i) * Cc + x0 + tx]);
  __syncthreads();
  for (int i = 0; i < 32; i += 8)
    out[(size_t)(x0 + ty + i) * Rr + y0 + tx] = tile[tx][ty + i];
}

// ===================== GEMM: C[M,N] = A[M,K] @ Bt[N,K]^T, bf16 internal, fp32 acc =====================
// m97 tile/fragments + SINGLE-barrier counted-vmcnt ring (round-7: 354.3 us anchor).
// Round-10's LDS swizzle was a proven no-op (8 lanes/16B-slot is the b128 hardware
// floor; conflicts = b128 structural overhead) -- reverted.
//
// ROUND-11 CHANGE: ring depth D=4 with stage lead L=2 (was D=3, L=1). The chain
// model now fits every GEMM: per-iter time floored at staging latency / L. At L=1,
// ~600cy/iter -> MLP2 96 iters ~ 67 us, QKV 4.5 rounds x 24 iters ~ 68 us. L=2
// halves the latency term (~300cy/iter). Occupancy: TN=64 49KB -> 3 blocks/CU
// (rate 3/300 vs 4/600 = +50%); TN=128 64KB -> 2 blocks/CU (2/300 vs 3/600 = +33%).
//
// Safety (extends round-7 proof): STAGE(kt) writes slot (kt+2)%4, last read at iter
// kt-2. Any wave at barrier(kt-1) has executed MFMA(kt-2) (in-order issue + HW lgkm
// waits before MFMA) => reads(kt-2) complete on all waves before any wave's
// STAGE(kt). One s_barrier + one counted vmcnt per K-step; vmcnt(2*LPS) leaves the
// 2 newest stages in flight ACROSS the barrier (never vmcnt(0) in-loop). Tail iters
// stage dummies (k=kbeg) into dead slots so per-wave counts stay uniform; trailing
// vmcnt(0) drains before exit.
enum { M_QKV = 0, M_RES = 3, M_BRELU = 4, M_BRES = 5 };

template <int MODE, int TN>
__global__ __launch_bounds__(256) void gemm_bt(
    const short* __restrict__ A, const short* __restrict__ Bt,
    void* __restrict__ Cv, short* __restrict__ C2, short* __restrict__ C3,
    const float* __restrict__ res, const float* __restrict__ bias, int N, int K)
{
  constexpr int NT = TN / 32;             // B-frags per wave (4 or 2)
  alignas(16) __shared__ short As[4][128 * 32];
  alignas(16) __shared__ short Bs[4][TN * 32];
  const int tid = threadIdx.x;
  const int wave = tid >> 6, lane = tid & 63;
  const int quad = lane >> 4, l15 = lane & 15;
  const int m0 = blockIdx.x * 128, n0 = blockIdx.y * TN;
  const int mw = (wave & 1) * 64, nw = (wave >> 1) * (TN / 2);

  f32x4 acc[4][NT];
#pragma unroll
  for (int i = 0; i < 4; ++i)
#pragma unroll
    for (int j = 0; j < NT; ++j) acc[i][j] = f32x4{0.f, 0.f, 0.f, 0.f};

  const int srow = wave * 32 + (lane >> 2);
  const int scol = (lane & 3) * 8;
  const size_t arow = (size_t)(m0 + srow) * K + scol;
  const size_t brow128 = (size_t)(n0 + srow) * K + scol;
  const size_t brow64  = (size_t)(n0 + wave * 16 + (lane >> 2)) * K + scol;

  // stage K-step k0 into ring slot `buf` (LPS loads per wave, program-order fixed)
  auto STAGE = [&](int buf, int k0) {
    __builtin_amdgcn_global_load_lds(AS1(A + arow + k0),                AS3(As[buf] + (wave*32     ) * 32), 16, 0, 0);
    __builtin_amdgcn_global_load_lds(AS1(A + arow + k0 + (size_t)16*K), AS3(As[buf] + (wave*32 + 16) * 32), 16, 0, 0);
    if constexpr (TN == 128) {
      __builtin_amdgcn_global_load_lds(AS1(Bt + brow128 + k0),                AS3(Bs[buf] + (wave*32     ) * 32), 16, 0, 0);
      __builtin_amdgcn_global_load_lds(AS1(Bt + brow128 + k0 + (size_t)16*K), AS3(Bs[buf] + (wave*32 + 16) * 32), 16, 0, 0);
    } else {
      __builtin_amdgcn_global_load_lds(AS1(Bt + brow64 + k0), AS3(Bs[buf] + (wave*16) * 32), 16, 0, 0);
    }
  };

  STAGE(0, 0);                                  // stage lead L=2: slot kt%4 holds K-step kt
  STAGE(1, 32);

  int cb = 0;
  for (int k0 = 0; k0 < K; k0 += 32) {
    const int kn = k0 + 64;                     // K-step kt+2
    int sb = cb + 2; if (sb >= 4) sb -= 4;
    // pin: previous iter's ds_reads+MFMAs may not sink below the coming barrier
    __builtin_amdgcn_sched_barrier(0);
    STAGE(sb, kn < K ? kn : 0);                 // dummy (dead slot) at tail
    // leave the 2 newest stages in flight; oldest (cur slot) proven landed
    if constexpr (TN == 128) asm volatile("s_waitcnt vmcnt(8)" ::: "memory");
    else                     asm volatile("s_waitcnt vmcnt(6)" ::: "memory");
    __builtin_amdgcn_s_barrier();               // cur slot staged on ALL waves
    __builtin_amdgcn_sched_barrier(0);          // pin: reads stay below the barrier

    bfrag af[4], bfv[NT];
#pragma unroll
    for (int mt = 0; mt < 4; ++mt)  af[mt]  = *(const bfrag*)(As[cb] + (mw + mt*16 + l15) * 32 + quad * 8);
#pragma unroll
    for (int nt = 0; nt < NT; ++nt) bfv[nt] = *(const bfrag*)(Bs[cb] + (nw + nt*16 + l15) * 32 + quad * 8);
#pragma unroll
    for (int mt = 0; mt < 4; ++mt)
#pragma unroll
      for (int nt = 0; nt < NT; ++nt)
        acc[mt][nt] = MFMA16(af[mt], bfv[nt], acc[mt][nt]);

    cb = cb + 1; if (cb >= 4) cb -= 4;
  }
  asm volatile("s_waitcnt vmcnt(0)" ::: "memory");  // drain tail dummies before exit

  // epilogue: C/D layout col = lane&15, row = quad*4 + reg  [m89-verified]
#pragma unroll
  for (int mt = 0; mt < 4; ++mt) {
#pragma unroll
    for (int nt = 0; nt < NT; ++nt) {
      if (MODE == M_QKV) {
        const int gn = n0 + nw + nt*16 + l15;
        const int seg = gn / 768, gn2 = gn - seg * 768;
        const int gm0 = m0 + mw + mt*16 + quad*4;
        if (seg == 2) {
          // V^T output: 4 consecutive l -> one 8-B store
          const int bb = gm0 >> 12, l = gm0 & 4095, hh = gn2 >> 6, hd = gn2 & 63;
          s16x4 pk{f2b(acc[mt][nt][0]), f2b(acc[mt][nt][1]),
                   f2b(acc[mt][nt][2]), f2b(acc[mt][nt][3])};
          *(s16x4*)(&C3[(((size_t)(bb * NHEAD + hh)) * HDIM + hd) * SEQ + l]) = pk;
        } else {
#pragma unroll
          for (int r = 0; r < 4; ++r) {
            const float v = acc[mt][nt][r];
            if (seg == 0) ((short*)Cv)[(size_t)(gm0 + r) * 768 + gn2] = f2b(v * 0.125f);
            else          C2[(size_t)(gm0 + r) * 768 + gn2] = f2b(v);
          }
        }
      } else {
#pragma unroll
        for (int r = 0; r < 4; ++r) {
          const int gm = m0 + mw + mt*16 + quad*4 + r;
          const int gn = n0 + nw + nt*16 + l15;
          float v = acc[mt][nt][r];
          const size_t ci = (size_t)gm * N + gn;
          if (MODE == M_RES)   { ((float*)Cv)[ci] = v + res[ci]; }
          if (MODE == M_BRELU) { v += bias[gn]; ((short*)Cv)[ci] = f2b(v > 0.f ? v : 0.f); }
          if (MODE == M_BRES)  { ((float*)Cv)[ci] = v + bias[gn] + res[ci]; }
        }
      }
    }
  }
}

// ===================== flash-style BigBird attention (round-7 version) =====================
// Block-cooperative K/V LDS staging; K0,K1,V0,V1 staged once per block into stride-68
// padded LDS via register round-trip, prefetched one iteration ahead.
// grid (item=78, head=12, batch=2). items 0..61: middle qb=item+1 (plan). 62..77:
// global qb 0/63 split into 8 partials x 8 consecutive K-blocks.
constexpr int PSTR = 72;  // P-tile row stride (shorts): b128 reads 2-way max
constexpr int KSTR = 68;  // K/V stage row stride (shorts): reads 2-way, writes clean

__global__ __launch_bounds__(256, 3) void attn_kernel(
    const short* __restrict__ q, const short* __restrict__ k,
    const short* __restrict__ vt, short* __restrict__ o,
    short* __restrict__ Opart, float* __restrict__ ml)
{
  alignas(16) __shared__ short KV[4][64 * KSTR];        // K0,K1,V0,V1   (34816 B)
  alignas(16) __shared__ short Pbuf[4][2 * 16 * PSTR];  // per-wave P    (18432 B)
  const int xi = blockIdx.x, h = blockIdx.y, b = blockIdx.z;
  const int tid = threadIdx.x, wave = tid >> 6, lane = tid & 63;
  const int quad = lane >> 4, l15 = lane & 15;
  const int r8 = lane >> 3, g8 = lane & 7;              // staging: row-in-8, granule

  int qb, part = 0, g = 0;
  bool partial;
  if (xi < 62) { qb = xi + 1; partial = false; }
  else { const int t = xi - 62; g = t >> 3; part = t & 7; qb = g ? 63 : 0; partial = true; }

  const short* qp = q + (size_t)(b * SEQ + qb * 64 + wave * 16 + l15) * D_MODEL + h * HDIM;
  const bfrag qf0 = *(const bfrag*)(qp + quad * 8);
  const bfrag qf1 = *(const bfrag*)(qp + 32 + quad * 8);

  const short* kb_base = k  + (size_t)b * SEQ * D_MODEL + h * HDIM;
  const short* vt_base = vt + ((size_t)(b * NHEAD + h)) * HDIM * SEQ;

  const int sr0 = wave * 16 + r8, sr1 = wave * 16 + 8 + r8;

  auto kidx = [&](int t, int which) -> int {
    const int tt = t > 3 ? 3 : t;
    return partial ? (part * 8 + 2 * tt + which) : g_plan.v[qb][2 * tt + which];
  };
  auto load8 = [&](int k0i, int k1i, s16x8* R) {
    const short* ka = kb_base + (size_t)k0i * 64 * D_MODEL + g8 * 8;
    const short* kbp = kb_base + (size_t)k1i * 64 * D_MODEL + g8 * 8;
    const short* va = vt_base + (size_t)k0i * 64 + g8 * 8;
    const short* vb = vt_base + (size_t)k1i * 64 + g8 * 8;
    R[0] = *(const s16x8*)(ka  + (size_t)sr0 * D_MODEL);
    R[1] = *(const s16x8*)(ka  + (size_t)sr1 * D_MODEL);
    R[2] = *(const s16x8*)(kbp + (size_t)sr0 * D_MODEL);
    R[3] = *(const s16x8*)(kbp + (size_t)sr1 * D_MODEL);
    R[4] = *(const s16x8*)(va  + (size_t)sr0 * SEQ);
    R[5] = *(const s16x8*)(va  + (size_t)sr1 * SEQ);
    R[6] = *(const s16x8*)(vb  + (size_t)sr0 * SEQ);
    R[7] = *(const s16x8*)(vb  + (size_t)sr1 * SEQ);
  };

  float m_r[4], l_r[4];
  f32x4 oacc[4];
#pragma unroll
  for (int r = 0; r < 4; ++r) { m_r[r] = -1e9f; l_r[r] = 0.f; }
#pragma unroll
  for (int nt = 0; nt < 4; ++nt) oacc[nt] = f32x4{0.f, 0.f, 0.f, 0.f};

  short* pb = &Pbuf[wave][0];

  s16x8 R[8];
  load8(kidx(0, 0), kidx(0, 1), R);

  for (int it = 0; it < 4; ++it) {
    __syncthreads();  // all waves done reading previous KV tiles
#pragma unroll
    for (int bu = 0; bu < 4; ++bu) {
      *(s16x8*)(&KV[bu][sr0 * KSTR + g8 * 8]) = R[2 * bu];
      *(s16x8*)(&KV[bu][sr1 * KSTR + g8 * 8]) = R[2 * bu + 1];
    }
    __syncthreads();  // staging visible to all waves

    load8(kidx(it + 1, 0), kidx(it + 1, 1), R);

    // ---- S0, S1 = Q K^T from LDS ----
    f32x4 s0[4], s1[4];
#pragma unroll
    for (int nt = 0; nt < 4; ++nt) {
      const int fr = (nt * 16 + l15) * KSTR + quad * 8;
      const bfrag ka0 = *(const bfrag*)(&KV[0][fr]);
      const bfrag ka1 = *(const bfrag*)(&KV[0][fr + 32]);
      const bfrag kb0 = *(const bfrag*)(&KV[1][fr]);
      const bfrag kb1 = *(const bfrag*)(&KV[1][fr + 32]);
      s0[nt] = f32x4{0.f,0.f,0.f,0.f}; s1[nt] = f32x4{0.f,0.f,0.f,0.f};
      s0[nt] = MFMA16(qf0, ka0, s0[nt]); s0[nt] = MFMA16(qf1, ka1, s0[nt]);
      s1[nt] = MFMA16(qf0, kb0, s1[nt]); s1[nt] = MFMA16(qf1, kb1, s1[nt]);
    }

    // ---- combined online softmax over 128 keys ----
    float alpha[4];
#pragma unroll
    for (int r = 0; r < 4; ++r) {
      float v = fmaxf(fmaxf(fmaxf(s0[0][r], s0[1][r]), fmaxf(s0[2][r], s0[3][r])),
                      fmaxf(fmaxf(s1[0][r], s1[1][r]), fmaxf(s1[2][r], s1[3][r])));
      v = fmaxf(v, __shfl_xor(v, 1));
      v = fmaxf(v, __shfl_xor(v, 2));
      v = fmaxf(v, __shfl_xor(v, 4));
      v = fmaxf(v, __shfl_xor(v, 8));
      const float mn = fmaxf(m_r[r], v);
      alpha[r] = __expf(m_r[r] - mn);
      m_r[r] = mn;
    }
    float psum[4] = {0.f, 0.f, 0.f, 0.f};
#pragma unroll
    for (int nt = 0; nt < 4; ++nt)
#pragma unroll
      for (int r = 0; r < 4; ++r) {
        const float p0 = __expf(s0[nt][r] - m_r[r]);
        const float p1 = __expf(s1[nt][r] - m_r[r]);
        s0[nt][r] = p0; s1[nt][r] = p1;
        psum[r] += p0 + p1;
      }
#pragma unroll
    for (int r = 0; r < 4; ++r) {
      float v = psum[r];
      v += __shfl_xor(v, 1); v += __shfl_xor(v, 2);
      v += __shfl_xor(v, 4); v += __shfl_xor(v, 8);
      l_r[r] = l_r[r] * alpha[r] + v;
    }

    // ---- P0,P1: C-layout -> A-layout via per-wave LDS ----
#pragma unroll
    for (int nt = 0; nt < 4; ++nt)
#pragma unroll
      for (int r = 0; r < 4; ++r) {
        pb[(quad * 4 + r) * PSTR + nt * 16 + l15]             = f2b(s0[nt][r]);
        pb[16 * PSTR + (quad * 4 + r) * PSTR + nt * 16 + l15] = f2b(s1[nt][r]);
      }

    // ---- O = alpha*O + P0 V0 + P1 V1 (V from LDS) ----
#pragma unroll
    for (int nt = 0; nt < 4; ++nt)
#pragma unroll
      for (int r = 0; r < 4; ++r) oacc[nt][r] *= alpha[r];
#pragma unroll
    for (int s = 0; s < 2; ++s) {
      const bfrag pf0 = *(const bfrag*)(pb + l15 * PSTR + s * 32 + quad * 8);
      const bfrag pf1 = *(const bfrag*)(pb + 16 * PSTR + l15 * PSTR + s * 32 + quad * 8);
#pragma unroll
      for (int nt = 0; nt < 4; ++nt) {
        const int fr = (nt * 16 + l15) * KSTR + s * 32 + quad * 8;
        const bfrag vf0 = *(const bfrag*)(&KV[2][fr]);
        const bfrag vf1 = *(const bfrag*)(&KV[3][fr]);
        oacc[nt] = MFMA16(pf0, vf0, oacc[nt]);
        oacc[nt] = MFMA16(pf1, vf1, oacc[nt]);
      }
    }
  }

  if (!partial) {
    short* op = o + (size_t)(b * SEQ + qb * 64 + wave * 16) * D_MODEL + h * HDIM;
#pragma unroll
    for (int r = 0; r < 4; ++r) {
      const float inv = 1.f / l_r[r];
#pragma unroll
      for (int nt = 0; nt < 4; ++nt)
        op[(size_t)(quad * 4 + r) * D_MODEL + nt * 16 + l15] = f2b(oacc[nt][r] * inv);
    }
  } else {
    const int pi = ((b * NHEAD + h) * 2 + g) * 8 + part;
    short* Op = Opart + (size_t)pi * 4096;
    float* mp = ml + (size_t)pi * 128;
#pragma unroll
    for (int r = 0; r < 4; ++r) {
      const int row = wave * 16 + quad * 4 + r;
#pragma unroll
      for (int nt = 0; nt < 4; ++nt)
        Op[row * 64 + nt * 16 + l15] = f2b(oacc[nt][r]);
      if (l15 == 0) { mp[row] = m_r[r]; mp[64 + row] = l_r[r]; }
    }
  }
}

// ===================== merge partials for global q-blocks =====================
__global__ __launch_bounds__(256) void attn_merge(
    const short* __restrict__ Opart, const float* __restrict__ ml,
    short* __restrict__ o)
{
  const int bi = blockIdx.x;
  const int g = bi & 1, h = (bi >> 1) % NHEAD, b = bi / (2 * NHEAD);
  const int qb = g ? 63 : 0;
  const int pi0 = bi * 8;
#pragma unroll
  for (int e = 0; e < 16; ++e) {
    const int idx = threadIdx.x + e * 256;
    const int r = idx >> 6, c = idx & 63;
    float ms = -1e9f;
#pragma unroll
    for (int p = 0; p < 8; ++p) ms = fmaxf(ms, ml[(size_t)(pi0 + p) * 128 + r]);
    float lsum = 0.f, osum = 0.f;
#pragma unroll
    for (int p = 0; p < 8; ++p) {
      const float w = __expf(ml[(size_t)(pi0 + p) * 128 + r] - ms);
      lsum += w * ml[(size_t)(pi0 + p) * 128 + 64 + r];
      osum += w * b2f(Opart[(size_t)(pi0 + p) * 4096 + idx]);
    }
    o[(size_t)(b * SEQ + qb * 64 + r) * D_MODEL + h * HDIM + c] = f2b(osum / lsum);
  }
}

// ===================== launch =====================
extern "C" void kernel_launch(void* const* d_in, const int* in_sizes, int n_in,
                              void* d_out, int out_size, void* d_ws, size_t ws_size,
                              hipStream_t stream) {
  (void)in_sizes; (void)n_in; (void)out_size; (void)ws_size;
  const float* x    = (const float*)d_in[0];
  const float* ln1s = (const float*)d_in[1];
  const float* ln1b = (const float*)d_in[2];
  const float* Wq   = (const float*)d_in[3];
  const float* Wk   = (const float*)d_in[4];
  const float* Wv   = (const float*)d_in[5];
  const float* Wo   = (const float*)d_in[6];
  const float* ln2s = (const float*)d_in[7];
  const float* ln2b = (const float*)d_in[8];
  const float* W1   = (const float*)d_in[9];
  const float* b1   = (const float*)d_in[10];
  const float* W2   = (const float*)d_in[11];
  const float* b2   = (const float*)d_in[12];
  float* out = (float*)d_out;

  // ws layout (~77.1 MiB): weightsT (14.2) | hbuf (12.6) | BIG 4x12.6 (tbuf)
  short* WqT  = (short*)((char*)d_ws + 256);
  short* WkT  = WqT  + 768 * 768;          // WqT|WkT|WvT contiguous => fused QKV Bt[2304][768]
  short* WvT  = WkT  + 768 * 768;
  short* WoT  = WvT  + 768 * 768;
  short* W1T  = WoT  + 768 * 768;          // (3072,768)
  short* W2T  = W1T  + (size_t)3072 * 768; // (768,3072)
  short* hbuf = W2T  + (size_t)3072 * 768;
  short* qbuf = hbuf + (size_t)ROWS * D_MODEL;
  short* kbuf = qbuf + (size_t)ROWS * D_MODEL;
  short* vtb  = kbuf + (size_t)ROWS * D_MODEL;
  short* obuf = vtb  + (size_t)ROWS * D_MODEL;
  short* tbuf = qbuf;   // MLP intermediate spans qbuf..obuf (4*ROWS*D_MODEL == ROWS*DFF)
  // attention partials in hbuf (dead between QKV GEMM and ln2): 3.3 MB
  short* Opart = hbuf;
  float* mlbuf = (float*)(hbuf + (size_t)384 * 4096);

  TrArgs ta;
  ta.src[0] = Wq; ta.src[1] = Wk; ta.src[2] = Wv; ta.src[3] = Wo; ta.src[4] = W1; ta.src[5] = W2;
  ta.dst[0] = WqT; ta.dst[1] = WkT; ta.dst[2] = WvT; ta.dst[3] = WoT; ta.dst[4] = W1T; ta.dst[5] = W2T;
  tr_all<<<6912, 256, 0, stream>>>(ta);

  ln_kernel<<<ROWS, 256, 0, stream>>>(x, ln1s, ln1b, hbuf);

  // QKV: M=8192, N=2304, K=768
  gemm_bt<M_QKV, 128><<<dim3(64, 18), 256, 0, stream>>>(hbuf, WqT, qbuf, kbuf, vtb, nullptr, nullptr, 2304, 768);

  attn_kernel<<<dim3(78, 12, 2), 256, 0, stream>>>(qbuf, kbuf, vtb, obuf, Opart, mlbuf);
  attn_merge<<<48, 256, 0, stream>>>(Opart, mlbuf, obuf);

  // attn out-proj + residual: M=8192, N=768, K=768 -> out = proj + x  (x1)
  gemm_bt<M_RES, 64><<<dim3(64, 12), 256, 0, stream>>>(obuf, WoT, out, nullptr, nullptr, x, nullptr, 768, 768);

  ln_kernel<<<ROWS, 256, 0, stream>>>(out, ln2s, ln2b, hbuf);

  // MLP1: M=8192, N=3072, K=768
  gemm_bt<M_BRELU, 128><<<dim3(64, 24), 256, 0, stream>>>(hbuf, W1T, tbuf, nullptr, nullptr, nullptr, b1, 3072, 768);
  // MLP2: M=8192, N=768, K=3072
  gemm_bt<M_BRES, 64> <<<dim3(64, 12), 256, 0, stream>>>(tbuf, W2T, out, nullptr, nullptr, out, b2, 768, 3072);
}

// Round 12
// 363.503 us; speedup vs baseline: 1.0299x; 1.0299x over previous
//
#include <hip/hip_runtime.h>
#include <stdint.h>

// ===================== problem constants =====================
constexpr int D_MODEL = 768;
constexpr int SEQ     = 4096;
constexpr int NHEAD   = 12;
constexpr int HDIM    = 64;
constexpr int BATCH   = 2;
constexpr int DFF     = 3072;
constexpr int ROWS    = BATCH * SEQ;   // 8192

typedef __attribute__((ext_vector_type(8))) __bf16 bfrag;
typedef __attribute__((ext_vector_type(8))) short  s16x8;
typedef __attribute__((ext_vector_type(4))) short  s16x4;
typedef __attribute__((ext_vector_type(4))) float  f32x4;

#define MFMA16(a, b, c) __builtin_amdgcn_mfma_f32_16x16x32_bf16((a), (b), (c), 0, 0, 0)
#define AS1(p) ((__attribute__((address_space(1))) void*)(uintptr_t)(p))
#define AS3(p) ((__attribute__((address_space(3))) void*)(p))

__device__ __forceinline__ float b2f(short s) {
  union { unsigned u; float f; } c;
  c.u = ((unsigned)(unsigned short)s) << 16;
  return c.f;
}
__device__ __forceinline__ short f2b(float f) {
  union { float f; unsigned u; } c;
  c.f = f;
  unsigned r = c.u + 0x7fffu + ((c.u >> 16) & 1u);  // RNE (finite inputs only)
  return (short)(r >> 16);
}

// ===================== static BigBird plan (constexpr MT19937 == np.random.RandomState(0)) =====================
struct PlanT { int v[64][8]; };

struct MTRng {
  unsigned mt[624];
  int mti;
  constexpr MTRng() : mt{}, mti(624) {
    mt[0] = 0u;
    for (int i = 1; i < 624; ++i)
      mt[i] = 1812433253u * (mt[i-1] ^ (mt[i-1] >> 30)) + (unsigned)i;
  }
  constexpr unsigned next() {
    if (mti >= 624) {
      for (int i = 0; i < 624; ++i) {
        unsigned y = (mt[i] & 0x80000000u) | (mt[(i+1) % 624] & 0x7fffffffu);
        unsigned v = mt[(i+397) % 624] ^ (y >> 1);
        if (y & 1u) v ^= 0x9908b0dfu;
        mt[i] = v;
      }
      mti = 0;
    }
    unsigned y = mt[mti++];
    y ^= y >> 11;
    y ^= (y << 7)  & 0x9d2c5680u;
    y ^= (y << 15) & 0xefc60000u;
    y ^= y >> 18;
    return y;
  }
  constexpr unsigned interval(unsigned mx) {
    unsigned mask = mx;
    mask |= mask >> 1; mask |= mask >> 2; mask |= mask >> 4;
    mask |= mask >> 8; mask |= mask >> 16;
    unsigned v = next() & mask;
    while (v > mx) v = next() & mask;
    return v;
  }
};

constexpr PlanT make_plan() {
  PlanT P{};
  MTRng rng{};
  for (int i = 1; i <= 62; ++i) {
    int cand[64] = {}; int n = 0;
    for (int j = 0; j < 64; ++j) {
      if (j == 0 || j == 63 || j == i-1 || j == i || j == i+1) continue;
      cand[n++] = j;
    }
    int perm[64] = {};
    for (int p = 0; p < n; ++p) perm[p] = p;
    for (int p = n - 1; p > 0; --p) {
      int j = (int)rng.interval((unsigned)p);
      int t = perm[p]; perm[p] = perm[j]; perm[j] = t;
    }
    P.v[i][0] = 0;  P.v[i][1] = 63; P.v[i][2] = i-1; P.v[i][3] = i; P.v[i][4] = i+1;
    P.v[i][5] = cand[perm[0]]; P.v[i][6] = cand[perm[1]]; P.v[i][7] = cand[perm[2]];
  }
  return P;
}
constexpr PlanT h_plan = make_plan();
__constant__ PlanT g_plan = h_plan;

// ===================== layernorm (fp32 in, bf16 out) =====================
__global__ __launch_bounds__(256) void ln_kernel(
    const float* __restrict__ x, const float* __restrict__ sc,
    const float* __restrict__ bi, short* __restrict__ y)
{
  const int row = blockIdx.x, tid = threadIdx.x;
  const size_t base = (size_t)row * D_MODEL;
  float v0 = x[base + tid], v1 = x[base + tid + 256], v2 = x[base + tid + 512];
  float s  = v0 + v1 + v2;
  float s2 = v0*v0 + v1*v1 + v2*v2;
  for (int off = 1; off < 64; off <<= 1) {
    s  += __shfl_xor(s,  off);
    s2 += __shfl_xor(s2, off);
  }
  __shared__ float red[8];
  if ((tid & 63) == 0) { red[tid >> 6] = s; red[4 + (tid >> 6)] = s2; }
  __syncthreads();
  s  = red[0] + red[1] + red[2] + red[3];
  s2 = red[4] + red[5] + red[6] + red[7];
  const float mu  = s * (1.f / 768.f);
  const float var = s2 * (1.f / 768.f) - mu * mu;
  const float rs  = rsqrtf(var + 1e-6f);
  short* yr = y + base;
  yr[tid]       = f2b((v0 - mu) * rs * sc[tid]       + bi[tid]);
  yr[tid + 256] = f2b((v1 - mu) * rs * sc[tid + 256] + bi[tid + 256]);
  yr[tid + 512] = f2b((v2 - mu) * rs * sc[tid + 512] + bi[tid + 512]);
}

// ===================== fused weight transposes (fp32 R x C -> bf16 C x R), 1 dispatch =====================
struct TrArgs { const float* src[6]; short* dst[6]; };

__global__ __launch_bounds__(256) void tr_all(TrArgs a) {
  __shared__ short tile[32][33];
  const int idx = blockIdx.x;
  int w, bx, by, Rr, Cc;
  if (idx < 2304)      { w = idx / 576; int t = idx % 576;  bx = t % 24; by = t / 24; Rr = 768;  Cc = 768;  }
  else if (idx < 4608) { w = 4;         int t = idx - 2304; bx = t % 96; by = t / 96; Rr = 768;  Cc = 3072; }
  else                 { w = 5;         int t = idx - 4608; bx = t % 24; by = t / 24; Rr = 3072; Cc = 768;  }
  const float* in = a.src[w];
  short* out = a.dst[w];
  const int x0 = bx * 32, y0 = by * 32;
  const int tx = threadIdx.x & 31, ty = threadIdx.x >> 5;
  for (int i = 0; i < 32; i += 8)
    tile[ty + i][tx] = f2b(in[(size_t)(y0 + ty + i) * Cc + x0 + tx]);
  __syncthreads();
  for (int i = 0; i < 32; i += 8)
    out[(size_t)(x0 + ty + i) * Rr + y0 + tx] = tile[tx][ty + i];
}

// ===================== GEMM: C[M,N] = A[M,K] @ Bt[N,K]^T, bf16 internal, fp32 acc =====================
// m97 tile/fragments + SINGLE-barrier counted-vmcnt ring (round-7: 354.3 us anchor).
// Round-11 (D=4/L=2 without prefetch) regressed -> staging latency is hidden already;
// the exposed term is the per-iter ds_read->MFMA dependency (~150-200cy x iters).
//
// ROUND-12 CHANGE (TN=64 path only): REGISTER PREFETCH. D=4/L=2 ring (48KB -> still
// 3 blocks/CU); iter kt: {STAGE(kt+2); vmcnt(3); barrier; ds_read slot kt+1 -> spare
// reg set; MFMA on current reg set}. The MFMAs' operands were read one iteration ago
// and had a full barrier-wait to complete -> ds_read latency leaves the serial chain.
// 2-phase unrolled loop with NAMED reg sets (rule 20); NK even for both users (24,96).
// Ring safety: overwrite target (kt+2)%4 was last read at iter kt-3; its consuming
// MFMA ran at iter kt-2 behind a HW lgkm wait; two barriers separate that from any
// wave's STAGE(kt) -> no race. vmcnt(3) leaves the newest stage in flight (never 0
// in-loop); tail stages dummies into dead slots so counts stay uniform.
// TN=128 path: exact round-7 (D=3, L=1) -- keeps its 3 blocks/CU at 48KB.
enum { M_QKV = 0, M_RES = 3, M_BRELU = 4, M_BRES = 5 };

template <int MODE, int TN>
__global__ __launch_bounds__(256) void gemm_bt(
    const short* __restrict__ A, const short* __restrict__ Bt,
    void* __restrict__ Cv, short* __restrict__ C2, short* __restrict__ C3,
    const float* __restrict__ res, const float* __restrict__ bias, int N, int K)
{
  constexpr int NT    = TN / 32;             // B-frags per wave (4 or 2)
  constexpr int DEPTH = (TN == 64) ? 4 : 3;
  alignas(16) __shared__ short As[DEPTH][128 * 32];
  alignas(16) __shared__ short Bs[DEPTH][TN * 32];
  const int tid = threadIdx.x;
  const int wave = tid >> 6, lane = tid & 63;
  const int quad = lane >> 4, l15 = lane & 15;
  const int m0 = blockIdx.x * 128, n0 = blockIdx.y * TN;
  const int mw = (wave & 1) * 64, nw = (wave >> 1) * (TN / 2);

  f32x4 acc[4][NT];
#pragma unroll
  for (int i = 0; i < 4; ++i)
#pragma unroll
    for (int j = 0; j < NT; ++j) acc[i][j] = f32x4{0.f, 0.f, 0.f, 0.f};

  const int srow = wave * 32 + (lane >> 2);
  const int scol = (lane & 3) * 8;
  const size_t arow = (size_t)(m0 + srow) * K + scol;
  const size_t brow128 = (size_t)(n0 + srow) * K + scol;
  const size_t brow64  = (size_t)(n0 + wave * 16 + (lane >> 2)) * K + scol;

  // stage K-step k0 into ring slot `buf` (LPS loads per wave, program-order fixed)
  auto STAGE = [&](int buf, int k0) {
    __builtin_amdgcn_global_load_lds(AS1(A + arow + k0),                AS3(As[buf] + (wave*32     ) * 32), 16, 0, 0);
    __builtin_amdgcn_global_load_lds(AS1(A + arow + k0 + (size_t)16*K), AS3(As[buf] + (wave*32 + 16) * 32), 16, 0, 0);
    if constexpr (TN == 128) {
      __builtin_amdgcn_global_load_lds(AS1(Bt + brow128 + k0),                AS3(Bs[buf] + (wave*32     ) * 32), 16, 0, 0);
      __builtin_amdgcn_global_load_lds(AS1(Bt + brow128 + k0 + (size_t)16*K), AS3(Bs[buf] + (wave*32 + 16) * 32), 16, 0, 0);
    } else {
      __builtin_amdgcn_global_load_lds(AS1(Bt + brow64 + k0), AS3(Bs[buf] + (wave*16) * 32), 16, 0, 0);
    }
  };

  if constexpr (TN == 64) {
    // -------- register-prefetch pipeline: D=4, L=2, one barrier + vmcnt(3)/iter ----
    STAGE(0, 0);
    STAGE(1, 32);
    asm volatile("s_waitcnt vmcnt(3)" ::: "memory");   // slot0 landed (slot1 in flight)
    __builtin_amdgcn_s_barrier();
    __builtin_amdgcn_sched_barrier(0);

    bfrag afA[4], bfA[2], afB[4], bfB[2];
#pragma unroll
    for (int mt = 0; mt < 4; ++mt) afA[mt] = *(const bfrag*)(As[0] + (mw + mt*16 + l15) * 32 + quad * 8);
#pragma unroll
    for (int nt = 0; nt < 2; ++nt) bfA[nt] = *(const bfrag*)(Bs[0] + (nw + nt*16 + l15) * 32 + quad * 8);

    const int NK = K >> 5;                     // even for all users (24, 96)
    for (int kt = 0; kt < NK; kt += 2) {
      // ---- even sub-iter: compute set A (K-step kt), prefetch set B (kt+1) ----
      {
        const int k2 = (kt + 2) * 32;
        __builtin_amdgcn_sched_barrier(0);
        STAGE((kt + 2) & 3, k2 < K ? k2 : 0);  // dummy into dead slot at tail
        asm volatile("s_waitcnt vmcnt(3)" ::: "memory");  // slot kt+1 landed
        __builtin_amdgcn_s_barrier();
        __builtin_amdgcn_sched_barrier(0);
        const short* an = As[(kt + 1) & 3];
        const short* bn = Bs[(kt + 1) & 3];
#pragma unroll
        for (int mt = 0; mt < 4; ++mt) afB[mt] = *(const bfrag*)(an + (mw + mt*16 + l15) * 32 + quad * 8);
#pragma unroll
        for (int nt = 0; nt < 2; ++nt) bfB[nt] = *(const bfrag*)(bn + (nw + nt*16 + l15) * 32 + quad * 8);
#pragma unroll
        for (int mt = 0; mt < 4; ++mt)
#pragma unroll
          for (int nt = 0; nt < 2; ++nt)
            acc[mt][nt] = MFMA16(afA[mt], bfA[nt], acc[mt][nt]);
      }
      // ---- odd sub-iter: compute set B (kt+1), prefetch set A (kt+2) ----
      {
        const int k2 = (kt + 3) * 32;
        __builtin_amdgcn_sched_barrier(0);
        STAGE((kt + 3) & 3, k2 < K ? k2 : 0);
        asm volatile("s_waitcnt vmcnt(3)" ::: "memory");  // slot kt+2 landed
        __builtin_amdgcn_s_barrier();
        __builtin_amdgcn_sched_barrier(0);
        const short* an = As[(kt + 2) & 3];
        const short* bn = Bs[(kt + 2) & 3];
#pragma unroll
        for (int mt = 0; mt < 4; ++mt) afA[mt] = *(const bfrag*)(an + (mw + mt*16 + l15) * 32 + quad * 8);
#pragma unroll
        for (int nt = 0; nt < 2; ++nt) bfA[nt] = *(const bfrag*)(bn + (nw + nt*16 + l15) * 32 + quad * 8);
#pragma unroll
        for (int mt = 0; mt < 4; ++mt)
#pragma unroll
          for (int nt = 0; nt < 2; ++nt)
            acc[mt][nt] = MFMA16(afB[mt], bfB[nt], acc[mt][nt]);
      }
    }
    asm volatile("s_waitcnt vmcnt(0)" ::: "memory");  // drain tail dummies before exit
  } else {
    // -------- round-7 single-barrier ring: D=3, L=1, vmcnt(4)/iter ----------------
    STAGE(0, 0);
    int cb = 0;
    for (int k0 = 0; k0 < K; k0 += 32) {
      const int kn = k0 + 32;
      int sb = cb + 1; if (sb >= 3) sb -= 3;
      __builtin_amdgcn_sched_barrier(0);
      STAGE(sb, kn < K ? kn : 0);
      asm volatile("s_waitcnt vmcnt(4)" ::: "memory");
      __builtin_amdgcn_s_barrier();
      __builtin_amdgcn_sched_barrier(0);

      bfrag af[4], bfv[NT];
#pragma unroll
      for (int mt = 0; mt < 4; ++mt)  af[mt]  = *(const bfrag*)(As[cb] + (mw + mt*16 + l15) * 32 + quad * 8);
#pragma unroll
      for (int nt = 0; nt < NT; ++nt) bfv[nt] = *(const bfrag*)(Bs[cb] + (nw + nt*16 + l15) * 32 + quad * 8);
#pragma unroll
      for (int mt = 0; mt < 4; ++mt)
#pragma unroll
        for (int nt = 0; nt < NT; ++nt)
          acc[mt][nt] = MFMA16(af[mt], bfv[nt], acc[mt][nt]);

      cb = sb;
    }
    asm volatile("s_waitcnt vmcnt(0)" ::: "memory");
  }

  // epilogue: C/D layout col = lane&15, row = quad*4 + reg  [m89-verified]
#pragma unroll
  for (int mt = 0; mt < 4; ++mt) {
#pragma unroll
    for (int nt = 0; nt < NT; ++nt) {
      if (MODE == M_QKV) {
        const int gn = n0 + nw + nt*16 + l15;
        const int seg = gn / 768, gn2 = gn - seg * 768;
        const int gm0 = m0 + mw + mt*16 + quad*4;
        if (seg == 2) {
          // V^T output: 4 consecutive l -> one 8-B store
          const int bb = gm0 >> 12, l = gm0 & 4095, hh = gn2 >> 6, hd = gn2 & 63;
          s16x4 pk{f2b(acc[mt][nt][0]), f2b(acc[mt][nt][1]),
                   f2b(acc[mt][nt][2]), f2b(acc[mt][nt][3])};
          *(s16x4*)(&C3[(((size_t)(bb * NHEAD + hh)) * HDIM + hd) * SEQ + l]) = pk;
        } else {
#pragma unroll
          for (int r = 0; r < 4; ++r) {
            const float v = acc[mt][nt][r];
            if (seg == 0) ((short*)Cv)[(size_t)(gm0 + r) * 768 + gn2] = f2b(v * 0.125f);
            else          C2[(size_t)(gm0 + r) * 768 + gn2] = f2b(v);
          }
        }
      } else {
#pragma unroll
        for (int r = 0; r < 4; ++r) {
          const int gm = m0 + mw + mt*16 + quad*4 + r;
          const int gn = n0 + nw + nt*16 + l15;
          float v = acc[mt][nt][r];
          const size_t ci = (size_t)gm * N + gn;
          if (MODE == M_RES)   { ((float*)Cv)[ci] = v + res[ci]; }
          if (MODE == M_BRELU) { v += bias[gn]; ((short*)Cv)[ci] = f2b(v > 0.f ? v : 0.f); }
          if (MODE == M_BRES)  { ((float*)Cv)[ci] = v + bias[gn] + res[ci]; }
        }
      }
    }
  }
}

// ===================== flash-style BigBird attention (round-7 version) =====================
// Block-cooperative K/V LDS staging; K0,K1,V0,V1 staged once per block into stride-68
// padded LDS via register round-trip, prefetched one iteration ahead.
// grid (item=78, head=12, batch=2). items 0..61: middle qb=item+1 (plan). 62..77:
// global qb 0/63 split into 8 partials x 8 consecutive K-blocks.
constexpr int PSTR = 72;  // P-tile row stride (shorts): b128 reads 2-way max
constexpr int KSTR = 68;  // K/V stage row stride (shorts): reads 2-way, writes clean

__global__ __launch_bounds__(256, 3) void attn_kernel(
    const short* __restrict__ q, const short* __restrict__ k,
    const short* __restrict__ vt, short* __restrict__ o,
    short* __restrict__ Opart, float* __restrict__ ml)
{
  alignas(16) __shared__ short KV[4][64 * KSTR];        // K0,K1,V0,V1   (34816 B)
  alignas(16) __shared__ short Pbuf[4][2 * 16 * PSTR];  // per-wave P    (18432 B)
  const int xi = blockIdx.x, h = blockIdx.y, b = blockIdx.z;
  const int tid = threadIdx.x, wave = tid >> 6, lane = tid & 63;
  const int quad = lane >> 4, l15 = lane & 15;
  const int r8 = lane >> 3, g8 = lane & 7;              // staging: row-in-8, granule

  int qb, part = 0, g = 0;
  bool partial;
  if (xi < 62) { qb = xi + 1; partial = false; }
  else { const int t = xi - 62; g = t >> 3; part = t & 7; qb = g ? 63 : 0; partial = true; }

  const short* qp = q + (size_t)(b * SEQ + qb * 64 + wave * 16 + l15) * D_MODEL + h * HDIM;
  const bfrag qf0 = *(const bfrag*)(qp + quad * 8);
  const bfrag qf1 = *(const bfrag*)(qp + 32 + quad * 8);

  const short* kb_base = k  + (size_t)b * SEQ * D_MODEL + h * HDIM;
  const short* vt_base = vt + ((size_t)(b * NHEAD + h)) * HDIM * SEQ;

  const int sr0 = wave * 16 + r8, sr1 = wave * 16 + 8 + r8;

  auto kidx = [&](int t, int which) -> int {
    const int tt = t > 3 ? 3 : t;
    return partial ? (part * 8 + 2 * tt + which) : g_plan.v[qb][2 * tt + which];
  };
  auto load8 = [&](int k0i, int k1i, s16x8* R) {
    const short* ka = kb_base + (size_t)k0i * 64 * D_MODEL + g8 * 8;
    const short* kbp = kb_base + (size_t)k1i * 64 * D_MODEL + g8 * 8;
    const short* va = vt_base + (size_t)k0i * 64 + g8 * 8;
    const short* vb = vt_base + (size_t)k1i * 64 + g8 * 8;
    R[0] = *(const s16x8*)(ka  + (size_t)sr0 * D_MODEL);
    R[1] = *(const s16x8*)(ka  + (size_t)sr1 * D_MODEL);
    R[2] = *(const s16x8*)(kbp + (size_t)sr0 * D_MODEL);
    R[3] = *(const s16x8*)(kbp + (size_t)sr1 * D_MODEL);
    R[4] = *(const s16x8*)(va  + (size_t)sr0 * SEQ);
    R[5] = *(const s16x8*)(va  + (size_t)sr1 * SEQ);
    R[6] = *(const s16x8*)(vb  + (size_t)sr0 * SEQ);
    R[7] = *(const s16x8*)(vb  + (size_t)sr1 * SEQ);
  };

  float m_r[4], l_r[4];
  f32x4 oacc[4];
#pragma unroll
  for (int r = 0; r < 4; ++r) { m_r[r] = -1e9f; l_r[r] = 0.f; }
#pragma unroll
  for (int nt = 0; nt < 4; ++nt) oacc[nt] = f32x4{0.f, 0.f, 0.f, 0.f};

  short* pb = &Pbuf[wave][0];

  s16x8 R[8];
  load8(kidx(0, 0), kidx(0, 1), R);

  for (int it = 0; it < 4; ++it) {
    __syncthreads();  // all waves done reading previous KV tiles
#pragma unroll
    for (int bu = 0; bu < 4; ++bu) {
      *(s16x8*)(&KV[bu][sr0 * KSTR + g8 * 8]) = R[2 * bu];
      *(s16x8*)(&KV[bu][sr1 * KSTR + g8 * 8]) = R[2 * bu + 1];
    }
    __syncthreads();  // staging visible to all waves

    load8(kidx(it + 1, 0), kidx(it + 1, 1), R);

    // ---- S0, S1 = Q K^T from LDS ----
    f32x4 s0[4], s1[4];
#pragma unroll
    for (int nt = 0; nt < 4; ++nt) {
      const int fr = (nt * 16 + l15) * KSTR + quad * 8;
      const bfrag ka0 = *(const bfrag*)(&KV[0][fr]);
      const bfrag ka1 = *(const bfrag*)(&KV[0][fr + 32]);
      const bfrag kb0 = *(const bfrag*)(&KV[1][fr]);
      const bfrag kb1 = *(const bfrag*)(&KV[1][fr + 32]);
      s0[nt] = f32x4{0.f,0.f,0.f,0.f}; s1[nt] = f32x4{0.f,0.f,0.f,0.f};
      s0[nt] = MFMA16(qf0, ka0, s0[nt]); s0[nt] = MFMA16(qf1, ka1, s0[nt]);
      s1[nt] = MFMA16(qf0, kb0, s1[nt]); s1[nt] = MFMA16(qf1, kb1, s1[nt]);
    }

    // ---- combined online softmax over 128 keys ----
    float alpha[4];
#pragma unroll
    for (int r = 0; r < 4; ++r) {
      float v = fmaxf(fmaxf(fmaxf(s0[0][r], s0[1][r]), fmaxf(s0[2][r], s0[3][r])),
                      fmaxf(fmaxf(s1[0][r], s1[1][r]), fmaxf(s1[2][r], s1[3][r])));
      v = fmaxf(v, __shfl_xor(v, 1));
      v = fmaxf(v, __shfl_xor(v, 2));
      v = fmaxf(v, __shfl_xor(v, 4));
      v = fmaxf(v, __shfl_xor(v, 8));
      const float mn = fmaxf(m_r[r], v);
      alpha[r] = __expf(m_r[r] - mn);
      m_r[r] = mn;
    }
    float psum[4] = {0.f, 0.f, 0.f, 0.f};
#pragma unroll
    for (int nt = 0; nt < 4; ++nt)
#pragma unroll
      for (int r = 0; r < 4; ++r) {
        const float p0 = __expf(s0[nt][r] - m_r[r]);
        const float p1 = __expf(s1[nt][r] - m_r[r]);
        s0[nt][r] = p0; s1[nt][r] = p1;
        psum[r] += p0 + p1;
      }
#pragma unroll
    for (int r = 0; r < 4; ++r) {
      float v = psum[r];
      v += __shfl_xor(v, 1); v += __shfl_xor(v, 2);
      v += __shfl_xor(v, 4); v += __shfl_xor(v, 8);
      l_r[r] = l_r[r] * alpha[r] + v;
    }

    // ---- P0,P1: C-layout -> A-layout via per-wave LDS ----
#pragma unroll
    for (int nt = 0; nt < 4; ++nt)
#pragma unroll
      for (int r = 0; r < 4; ++r) {
        pb[(quad * 4 + r) * PSTR + nt * 16 + l15]             = f2b(s0[nt][r]);
        pb[16 * PSTR + (quad * 4 + r) * PSTR + nt * 16 + l15] = f2b(s1[nt][r]);
      }

    // ---- O = alpha*O + P0 V0 + P1 V1 (V from LDS) ----
#pragma unroll
    for (int nt = 0; nt < 4; ++nt)
#pragma unroll
      for (int r = 0; r < 4; ++r) oacc[nt][r] *= alpha[r];
#pragma unroll
    for (int s = 0; s < 2; ++s) {
      const bfrag pf0 = *(const bfrag*)(pb + l15 * PSTR + s * 32 + quad * 8);
      const bfrag pf1 = *(const bfrag*)(pb + 16 * PSTR + l15 * PSTR + s * 32 + quad * 8);
#pragma unroll
      for (int nt = 0; nt < 4; ++nt) {
        const int fr = (nt * 16 + l15) * KSTR + s * 32 + quad * 8;
        const bfrag vf0 = *(const bfrag*)(&KV[2][fr]);
        const bfrag vf1 = *(const bfrag*)(&KV[3][fr]);
        oacc[nt] = MFMA16(pf0, vf0, oacc[nt]);
        oacc[nt] = MFMA16(pf1, vf1, oacc[nt]);
      }
    }
  }

  if (!partial) {
    short* op = o + (size_t)(b * SEQ + qb * 64 + wave * 16) * D_MODEL + h * HDIM;
#pragma unroll
    for (int r = 0; r < 4; ++r) {
      const float inv = 1.f / l_r[r];
#pragma unroll
      for (int nt = 0; nt < 4; ++nt)
        op[(size_t)(quad * 4 + r) * D_MODEL + nt * 16 + l15] = f2b(oacc[nt][r] * inv);
    }
  } else {
    const int pi = ((b * NHEAD + h) * 2 + g) * 8 + part;
    short* Op = Opart + (size_t)pi * 4096;
    float* mp = ml + (size_t)pi * 128;
#pragma unroll
    for (int r = 0; r < 4; ++r) {
      const int row = wave * 16 + quad * 4 + r;
#pragma unroll
      for (int nt = 0; nt < 4; ++nt)
        Op[row * 64 + nt * 16 + l15] = f2b(oacc[nt][r]);
      if (l15 == 0) { mp[row] = m_r[r]; mp[64 + row] = l_r[r]; }
    }
  }
}

// ===================== merge partials for global q-blocks =====================
__global__ __launch_bounds__(256) void attn_merge(
    const short* __restrict__ Opart, const float* __restrict__ ml,
    short* __restrict__ o)
{
  const int bi = blockIdx.x;
  const int g = bi & 1, h = (bi >> 1) % NHEAD, b = bi / (2 * NHEAD);
  const int qb = g ? 63 : 0;
  const int pi0 = bi * 8;
#pragma unroll
  for (int e = 0; e < 16; ++e) {
    const int idx = threadIdx.x + e * 256;
    const int r = idx >> 6, c = idx & 63;
    float ms = -1e9f;
#pragma unroll
    for (int p = 0; p < 8; ++p) ms = fmaxf(ms, ml[(size_t)(pi0 + p) * 128 + r]);
    float lsum = 0.f, osum = 0.f;
#pragma unroll
    for (int p = 0; p < 8; ++p) {
      const float w = __expf(ml[(size_t)(pi0 + p) * 128 + r] - ms);
      lsum += w * ml[(size_t)(pi0 + p) * 128 + 64 + r];
      osum += w * b2f(Opart[(size_t)(pi0 + p) * 4096 + idx]);
    }
    o[(size_t)(b * SEQ + qb * 64 + r) * D_MODEL + h * HDIM + c] = f2b(osum / lsum);
  }
}

// ===================== launch =====================
extern "C" void kernel_launch(void* const* d_in, const int* in_sizes, int n_in,
                              void* d_out, int out_size, void* d_ws, size_t ws_size,
                              hipStream_t stream) {
  (void)in_sizes; (void)n_in; (void)out_size; (void)ws_size;
  const float* x    = (const float*)d_in[0];
  const float* ln1s = (const float*)d_in[1];
  const float* ln1b = (const float*)d_in[2];
  const float* Wq   = (const float*)d_in[3];
  const float* Wk   = (const float*)d_in[4];
  const float* Wv   = (const float*)d_in[5];
  const float* Wo   = (const float*)d_in[6];
  const float* ln2s = (const float*)d_in[7];
  const float* ln2b = (const float*)d_in[8];
  const float* W1   = (const float*)d_in[9];
  const float* b1   = (const float*)d_in[10];
  const float* W2   = (const float*)d_in[11];
  const float* b2   = (const float*)d_in[12];
  float* out = (float*)d_out;

  // ws layout (~77.1 MiB): weightsT (14.2) | hbuf (12.6) | BIG 4x12.6 (tbuf)
  short* WqT  = (short*)((char*)d_ws + 256);
  short* WkT  = WqT  + 768 * 768;          // WqT|WkT|WvT contiguous => fused QKV Bt[2304][768]
  short* WvT  = WkT  + 768 * 768;
  short* WoT  = WvT  + 768 * 768;
  short* W1T  = WoT  + 768 * 768;          // (3072,768)
  short* W2T  = W1T  + (size_t)3072 * 768; // (768,3072)
  short* hbuf = W2T  + (size_t)3072 * 768;
  short* qbuf = hbuf + (size_t)ROWS * D_MODEL;
  short* kbuf = qbuf + (size_t)ROWS * D_MODEL;
  short* vtb  = kbuf + (size_t)ROWS * D_MODEL;
  short* obuf = vtb  + (size_t)ROWS * D_MODEL;
  short* tbuf = qbuf;   // MLP intermediate spans qbuf..obuf (4*ROWS*D_MODEL == ROWS*DFF)
  // attention partials in hbuf (dead between QKV GEMM and ln2): 3.3 MB
  short* Opart = hbuf;
  float* mlbuf = (float*)(hbuf + (size_t)384 * 4096);

  TrArgs ta;
  ta.src[0] = Wq; ta.src[1] = Wk; ta.src[2] = Wv; ta.src[3] = Wo; ta.src[4] = W1; ta.src[5] = W2;
  ta.dst[0] = WqT; ta.dst[1] = WkT; ta.dst[2] = WvT; ta.dst[3] = WoT; ta.dst[4] = W1T; ta.dst[5] = W2T;
  tr_all<<<6912, 256, 0, stream>>>(ta);

  ln_kernel<<<ROWS, 256, 0, stream>>>(x, ln1s, ln1b, hbuf);

  // QKV: M=8192, N=2304, K=768
  gemm_bt<M_QKV, 128><<<dim3(64, 18), 256, 0, stream>>>(hbuf, WqT, qbuf, kbuf, vtb, nullptr, nullptr, 2304, 768);

  attn_kernel<<<dim3(78, 12, 2), 256, 0, stream>>>(qbuf, kbuf, vtb, obuf, Opart, mlbuf);
  attn_merge<<<48, 256, 0, stream>>>(Opart, mlbuf, obuf);

  // attn out-proj + residual: M=8192, N=768, K=768 -> out = proj + x  (x1)
  gemm_bt<M_RES, 64><<<dim3(64, 12), 256, 0, stream>>>(obuf, WoT, out, nullptr, nullptr, x, nullptr, 768, 768);

  ln_kernel<<<ROWS, 256, 0, stream>>>(out, ln2s, ln2b, hbuf);

  // MLP1: M=8192, N=3072, K=768
  gemm_bt<M_BRELU, 128><<<dim3(64, 24), 256, 0, stream>>>(hbuf, W1T, tbuf, nullptr, nullptr, nullptr, b1, 3072, 768);
  // MLP2: M=8192, N=768, K=3072
  gemm_bt<M_BRES, 64> <<<dim3(64, 12), 256, 0, stream>>>(tbuf, W2T, out, nullptr, nullptr, out, b2, 768, 3072);
}

// Round 13
// 351.141 us; speedup vs baseline: 1.0661x; 1.0352x over previous
//
#include <hip/hip_runtime.h>
#include <stdint.h>

// ===================== problem constants =====================
constexpr int D_MODEL = 768;
constexpr int SEQ     = 4096;
constexpr int NHEAD   = 12;
constexpr int HDIM    = 64;
constexpr int BATCH   = 2;
constexpr int DFF     = 3072;
constexpr int ROWS    = BATCH * SEQ;   // 8192

typedef __attribute__((ext_vector_type(8))) __bf16 bfrag;
typedef __attribute__((ext_vector_type(8))) short  s16x8;
typedef __attribute__((ext_vector_type(4))) short  s16x4;
typedef __attribute__((ext_vector_type(4))) float  f32x4;

#define MFMA16(a, b, c) __builtin_amdgcn_mfma_f32_16x16x32_bf16((a), (b), (c), 0, 0, 0)
#define AS1(p) ((__attribute__((address_space(1))) void*)(uintptr_t)(p))
#define AS3(p) ((__attribute__((address_space(3))) void*)(p))

__device__ __forceinline__ float b2f(short s) {
  union { unsigned u; float f; } c;
  c.u = ((unsigned)(unsigned short)s) << 16;
  return c.f;
}
__device__ __forceinline__ short f2b(float f) {
  union { float f; unsigned u; } c;
  c.f = f;
  unsigned r = c.u + 0x7fffu + ((c.u >> 16) & 1u);  // RNE (finite inputs only)
  return (short)(r >> 16);
}

// ===================== static BigBird plan (constexpr MT19937 == np.random.RandomState(0)) =====================
struct PlanT { int v[64][8]; };

struct MTRng {
  unsigned mt[624];
  int mti;
  constexpr MTRng() : mt{}, mti(624) {
    mt[0] = 0u;
    for (int i = 1; i < 624; ++i)
      mt[i] = 1812433253u * (mt[i-1] ^ (mt[i-1] >> 30)) + (unsigned)i;
  }
  constexpr unsigned next() {
    if (mti >= 624) {
      for (int i = 0; i < 624; ++i) {
        unsigned y = (mt[i] & 0x80000000u) | (mt[(i+1) % 624] & 0x7fffffffu);
        unsigned v = mt[(i+397) % 624] ^ (y >> 1);
        if (y & 1u) v ^= 0x9908b0dfu;
        mt[i] = v;
      }
      mti = 0;
    }
    unsigned y = mt[mti++];
    y ^= y >> 11;
    y ^= (y << 7)  & 0x9d2c5680u;
    y ^= (y << 15) & 0xefc60000u;
    y ^= y >> 18;
    return y;
  }
  constexpr unsigned interval(unsigned mx) {
    unsigned mask = mx;
    mask |= mask >> 1; mask |= mask >> 2; mask |= mask >> 4;
    mask |= mask >> 8; mask |= mask >> 16;
    unsigned v = next() & mask;
    while (v > mx) v = next() & mask;
    return v;
  }
};

constexpr PlanT make_plan() {
  PlanT P{};
  MTRng rng{};
  for (int i = 1; i <= 62; ++i) {
    int cand[64] = {}; int n = 0;
    for (int j = 0; j < 64; ++j) {
      if (j == 0 || j == 63 || j == i-1 || j == i || j == i+1) continue;
      cand[n++] = j;
    }
    int perm[64] = {};
    for (int p = 0; p < n; ++p) perm[p] = p;
    for (int p = n - 1; p > 0; --p) {
      int j = (int)rng.interval((unsigned)p);
      int t = perm[p]; perm[p] = perm[j]; perm[j] = t;
    }
    P.v[i][0] = 0;  P.v[i][1] = 63; P.v[i][2] = i-1; P.v[i][3] = i; P.v[i][4] = i+1;
    P.v[i][5] = cand[perm[0]]; P.v[i][6] = cand[perm[1]]; P.v[i][7] = cand[perm[2]];
  }
  return P;
}
constexpr PlanT h_plan = make_plan();
__constant__ PlanT g_plan = h_plan;

// ===================== layernorm (fp32 in, bf16 out) — standalone (used for ln2) =====================
__global__ __launch_bounds__(256) void ln_kernel(
    const float* __restrict__ x, const float* __restrict__ sc,
    const float* __restrict__ bi, short* __restrict__ y)
{
  const int row = blockIdx.x, tid = threadIdx.x;
  const size_t base = (size_t)row * D_MODEL;
  float v0 = x[base + tid], v1 = x[base + tid + 256], v2 = x[base + tid + 512];
  float s  = v0 + v1 + v2;
  float s2 = v0*v0 + v1*v1 + v2*v2;
  for (int off = 1; off < 64; off <<= 1) {
    s  += __shfl_xor(s,  off);
    s2 += __shfl_xor(s2, off);
  }
  __shared__ float red[8];
  if ((tid & 63) == 0) { red[tid >> 6] = s; red[4 + (tid >> 6)] = s2; }
  __syncthreads();
  s  = red[0] + red[1] + red[2] + red[3];
  s2 = red[4] + red[5] + red[6] + red[7];
  const float mu  = s * (1.f / 768.f);
  const float var = s2 * (1.f / 768.f) - mu * mu;
  const float rs  = rsqrtf(var + 1e-6f);
  short* yr = y + base;
  yr[tid]       = f2b((v0 - mu) * rs * sc[tid]       + bi[tid]);
  yr[tid + 256] = f2b((v1 - mu) * rs * sc[tid + 256] + bi[tid + 256]);
  yr[tid + 512] = f2b((v2 - mu) * rs * sc[tid + 512] + bi[tid + 512]);
}

// ===================== merged pre-pass: weight transposes + ln1 in ONE dispatch =====================
// tr (blocks 0..6911) and ln1 (blocks 6912..15103) are fully independent (weights vs
// x) and both 256-thread -> one grid fills each other's dispatch tails and saves a
// launch gap. Branch is blockIdx-uniform (no divergence within a block).
struct TrArgs { const float* src[6]; short* dst[6]; };

__global__ __launch_bounds__(256) void pre_kernel(
    TrArgs a, const float* __restrict__ x, const float* __restrict__ sc,
    const float* __restrict__ bi, short* __restrict__ y)
{
  __shared__ short tile[32][33];
  __shared__ float red[8];
  if (blockIdx.x < 6912) {
    const int idx = blockIdx.x;
    int w, bx, by, Rr, Cc;
    if (idx < 2304)      { w = idx / 576; int t = idx % 576;  bx = t % 24; by = t / 24; Rr = 768;  Cc = 768;  }
    else if (idx < 4608) { w = 4;         int t = idx - 2304; bx = t % 96; by = t / 96; Rr = 768;  Cc = 3072; }
    else                 { w = 5;         int t = idx - 4608; bx = t % 24; by = t / 24; Rr = 3072; Cc = 768;  }
    const float* in = a.src[w];
    short* out = a.dst[w];
    const int x0 = bx * 32, y0 = by * 32;
    const int tx = threadIdx.x & 31, ty = threadIdx.x >> 5;
    for (int i = 0; i < 32; i += 8)
      tile[ty + i][tx] = f2b(in[(size_t)(y0 + ty + i) * Cc + x0 + tx]);
    __syncthreads();
    for (int i = 0; i < 32; i += 8)
      out[(size_t)(x0 + ty + i) * Rr + y0 + tx] = tile[tx][ty + i];
  } else {
    const int row = blockIdx.x - 6912, tid = threadIdx.x;
    const size_t base = (size_t)row * D_MODEL;
    float v0 = x[base + tid], v1 = x[base + tid + 256], v2 = x[base + tid + 512];
    float s  = v0 + v1 + v2;
    float s2 = v0*v0 + v1*v1 + v2*v2;
    for (int off = 1; off < 64; off <<= 1) {
      s  += __shfl_xor(s,  off);
      s2 += __shfl_xor(s2, off);
    }
    if ((tid & 63) == 0) { red[tid >> 6] = s; red[4 + (tid >> 6)] = s2; }
    __syncthreads();
    s  = red[0] + red[1] + red[2] + red[3];
    s2 = red[4] + red[5] + red[6] + red[7];
    const float mu  = s * (1.f / 768.f);
    const float var = s2 * (1.f / 768.f) - mu * mu;
    const float rs  = rsqrtf(var + 1e-6f);
    short* yr = y + base;
    yr[tid]       = f2b((v0 - mu) * rs * sc[tid]       + bi[tid]);
    yr[tid + 256] = f2b((v1 - mu) * rs * sc[tid + 256] + bi[tid + 256]);
    yr[tid + 512] = f2b((v2 - mu) * rs * sc[tid + 512] + bi[tid + 512]);
  }
}

// ===================== GEMM: C[M,N] = A[M,K] @ Bt[N,K]^T, bf16 internal, fp32 acc =====================
// ROUND-7 CONFIGURATION (session best, 354.3 us) — restored verbatim after rounds
// 8-12 falsified: direct-global attn K/V (r8, 2.5x regression), split-K+atomics
// (r9, traffic-bound loss), LDS swizzle (r10, no-op at the b128 floor), D=4/L=2
// (r11, occupancy/neutral loss), register prefetch (r12, neutral-negative).
//
// Structure: m97 tile/fragments + SINGLE-barrier counted-vmcnt ring. Stage lead L=1
// into D=3 ring: STAGE(kt) writes slot (kt+1)%3, last consumed at iter kt-2, whose
// reads completed before barrier(kt-1) on every wave (program order; iter-top
// sched_barrier(0) pins MFMAs above the barrier; HW lgkm waits precede them). One
// s_barrier + one vmcnt(LPS) per K-step; never vmcnt(0) in-loop. Tail iters stage
// dummies into dead slots so per-wave counts stay uniform; trailing vmcnt(0) drains.
enum { M_QKV = 0, M_RES = 3, M_BRELU = 4, M_BRES = 5 };

template <int MODE, int TN>
__global__ __launch_bounds__(256) void gemm_bt(
    const short* __restrict__ A, const short* __restrict__ Bt,
    void* __restrict__ Cv, short* __restrict__ C2, short* __restrict__ C3,
    const float* __restrict__ res, const float* __restrict__ bias, int N, int K)
{
  constexpr int NT = TN / 32;             // B-frags per wave (4 or 2)
  alignas(16) __shared__ short As[3][128 * 32];
  alignas(16) __shared__ short Bs[3][TN * 32];
  const int tid = threadIdx.x;
  const int wave = tid >> 6, lane = tid & 63;
  const int quad = lane >> 4, l15 = lane & 15;
  const int m0 = blockIdx.x * 128, n0 = blockIdx.y * TN;
  const int mw = (wave & 1) * 64, nw = (wave >> 1) * (TN / 2);

  f32x4 acc[4][NT];
#pragma unroll
  for (int i = 0; i < 4; ++i)
#pragma unroll
    for (int j = 0; j < NT; ++j) acc[i][j] = f32x4{0.f, 0.f, 0.f, 0.f};

  const int srow = wave * 32 + (lane >> 2);
  const int scol = (lane & 3) * 8;
  const size_t arow = (size_t)(m0 + srow) * K + scol;
  const size_t brow128 = (size_t)(n0 + srow) * K + scol;
  const size_t brow64  = (size_t)(n0 + wave * 16 + (lane >> 2)) * K + scol;

  // stage K-step k0 into ring slot `buf` (LPS loads per wave, program-order fixed)
  auto STAGE = [&](int buf, int k0) {
    __builtin_amdgcn_global_load_lds(AS1(A + arow + k0),                AS3(As[buf] + (wave*32     ) * 32), 16, 0, 0);
    __builtin_amdgcn_global_load_lds(AS1(A + arow + k0 + (size_t)16*K), AS3(As[buf] + (wave*32 + 16) * 32), 16, 0, 0);
    if constexpr (TN == 128) {
      __builtin_amdgcn_global_load_lds(AS1(Bt + brow128 + k0),                AS3(Bs[buf] + (wave*32     ) * 32), 16, 0, 0);
      __builtin_amdgcn_global_load_lds(AS1(Bt + brow128 + k0 + (size_t)16*K), AS3(Bs[buf] + (wave*32 + 16) * 32), 16, 0, 0);
    } else {
      __builtin_amdgcn_global_load_lds(AS1(Bt + brow64 + k0), AS3(Bs[buf] + (wave*16) * 32), 16, 0, 0);
    }
  };

  STAGE(0, 0);                                  // stage lead L=1: slot kt%3 holds K-step kt

  int cb = 0;
  for (int k0 = 0; k0 < K; k0 += 32) {
    const int kn = k0 + 32;
    int sb = cb + 1; if (sb >= 3) sb -= 3;
    // pin: previous iter's ds_reads+MFMAs may not sink below the coming barrier
    __builtin_amdgcn_sched_barrier(0);
    STAGE(sb, kn < K ? kn : 0);                 // dummy (dead slot) at tail
    // leave the new stage in flight; oldest (cur slot) proven landed
    if constexpr (TN == 128) asm volatile("s_waitcnt vmcnt(4)" ::: "memory");
    else                     asm volatile("s_waitcnt vmcnt(3)" ::: "memory");
    __builtin_amdgcn_s_barrier();               // cur slot staged on ALL waves
    __builtin_amdgcn_sched_barrier(0);          // pin: reads stay below the barrier

    bfrag af[4], bfv[NT];
#pragma unroll
    for (int mt = 0; mt < 4; ++mt)  af[mt]  = *(const bfrag*)(As[cb] + (mw + mt*16 + l15) * 32 + quad * 8);
#pragma unroll
    for (int nt = 0; nt < NT; ++nt) bfv[nt] = *(const bfrag*)(Bs[cb] + (nw + nt*16 + l15) * 32 + quad * 8);
#pragma unroll
    for (int mt = 0; mt < 4; ++mt)
#pragma unroll
      for (int nt = 0; nt < NT; ++nt)
        acc[mt][nt] = MFMA16(af[mt], bfv[nt], acc[mt][nt]);

    cb = sb;
  }
  asm volatile("s_waitcnt vmcnt(0)" ::: "memory");  // drain tail dummies before exit

  // epilogue: C/D layout col = lane&15, row = quad*4 + reg  [m89-verified]
#pragma unroll
  for (int mt = 0; mt < 4; ++mt) {
#pragma unroll
    for (int nt = 0; nt < NT; ++nt) {
      if (MODE == M_QKV) {
        const int gn = n0 + nw + nt*16 + l15;
        const int seg = gn / 768, gn2 = gn - seg * 768;
        const int gm0 = m0 + mw + mt*16 + quad*4;
        if (seg == 2) {
          // V^T output: 4 consecutive l -> one 8-B store
          const int bb = gm0 >> 12, l = gm0 & 4095, hh = gn2 >> 6, hd = gn2 & 63;
          s16x4 pk{f2b(acc[mt][nt][0]), f2b(acc[mt][nt][1]),
                   f2b(acc[mt][nt][2]), f2b(acc[mt][nt][3])};
          *(s16x4*)(&C3[(((size_t)(bb * NHEAD + hh)) * HDIM + hd) * SEQ + l]) = pk;
        } else {
#pragma unroll
          for (int r = 0; r < 4; ++r) {
            const float v = acc[mt][nt][r];
            if (seg == 0) ((short*)Cv)[(size_t)(gm0 + r) * 768 + gn2] = f2b(v * 0.125f);
            else          C2[(size_t)(gm0 + r) * 768 + gn2] = f2b(v);
          }
        }
      } else {
#pragma unroll
        for (int r = 0; r < 4; ++r) {
          const int gm = m0 + mw + mt*16 + quad*4 + r;
          const int gn = n0 + nw + nt*16 + l15;
          float v = acc[mt][nt][r];
          const size_t ci = (size_t)gm * N + gn;
          if (MODE == M_RES)   { ((float*)Cv)[ci] = v + res[ci]; }
          if (MODE == M_BRELU) { v += bias[gn]; ((short*)Cv)[ci] = f2b(v > 0.f ? v : 0.f); }
          if (MODE == M_BRES)  { ((float*)Cv)[ci] = v + bias[gn] + res[ci]; }
        }
      }
    }
  }
}

// ===================== flash-style BigBird attention (round-7 version) =====================
// Block-cooperative K/V LDS staging; K0,K1,V0,V1 staged once per block into stride-68
// padded LDS via register round-trip, prefetched one iteration ahead.
// grid (item=78, head=12, batch=2). items 0..61: middle qb=item+1 (plan). 62..77:
// global qb 0/63 split into 8 partials x 8 consecutive K-blocks.
constexpr int PSTR = 72;  // P-tile row stride (shorts): b128 reads 2-way max
constexpr int KSTR = 68;  // K/V stage row stride (shorts): reads 2-way, writes clean

__global__ __launch_bounds__(256, 3) void attn_kernel(
    const short* __restrict__ q, const short* __restrict__ k,
    const short* __restrict__ vt, short* __restrict__ o,
    short* __restrict__ Opart, float* __restrict__ ml)
{
  alignas(16) __shared__ short KV[4][64 * KSTR];        // K0,K1,V0,V1   (34816 B)
  alignas(16) __shared__ short Pbuf[4][2 * 16 * PSTR];  // per-wave P    (18432 B)
  const int xi = blockIdx.x, h = blockIdx.y, b = blockIdx.z;
  const int tid = threadIdx.x, wave = tid >> 6, lane = tid & 63;
  const int quad = lane >> 4, l15 = lane & 15;
  const int r8 = lane >> 3, g8 = lane & 7;              // staging: row-in-8, granule

  int qb, part = 0, g = 0;
  bool partial;
  if (xi < 62) { qb = xi + 1; partial = false; }
  else { const int t = xi - 62; g = t >> 3; part = t & 7; qb = g ? 63 : 0; partial = true; }

  const short* qp = q + (size_t)(b * SEQ + qb * 64 + wave * 16 + l15) * D_MODEL + h * HDIM;
  const bfrag qf0 = *(const bfrag*)(qp + quad * 8);
  const bfrag qf1 = *(const bfrag*)(qp + 32 + quad * 8);

  const short* kb_base = k  + (size_t)b * SEQ * D_MODEL + h * HDIM;
  const short* vt_base = vt + ((size_t)(b * NHEAD + h)) * HDIM * SEQ;

  const int sr0 = wave * 16 + r8, sr1 = wave * 16 + 8 + r8;

  auto kidx = [&](int t, int which) -> int {
    const int tt = t > 3 ? 3 : t;
    return partial ? (part * 8 + 2 * tt + which) : g_plan.v[qb][2 * tt + which];
  };
  auto load8 = [&](int k0i, int k1i, s16x8* R) {
    const short* ka = kb_base + (size_t)k0i * 64 * D_MODEL + g8 * 8;
    const short* kbp = kb_base + (size_t)k1i * 64 * D_MODEL + g8 * 8;
    const short* va = vt_base + (size_t)k0i * 64 + g8 * 8;
    const short* vb = vt_base + (size_t)k1i * 64 + g8 * 8;
    R[0] = *(const s16x8*)(ka  + (size_t)sr0 * D_MODEL);
    R[1] = *(const s16x8*)(ka  + (size_t)sr1 * D_MODEL);
    R[2] = *(const s16x8*)(kbp + (size_t)sr0 * D_MODEL);
    R[3] = *(const s16x8*)(kbp + (size_t)sr1 * D_MODEL);
    R[4] = *(const s16x8*)(va  + (size_t)sr0 * SEQ);
    R[5] = *(const s16x8*)(va  + (size_t)sr1 * SEQ);
    R[6] = *(const s16x8*)(vb  + (size_t)sr0 * SEQ);
    R[7] = *(const s16x8*)(vb  + (size_t)sr1 * SEQ);
  };

  float m_r[4], l_r[4];
  f32x4 oacc[4];
#pragma unroll
  for (int r = 0; r < 4; ++r) { m_r[r] = -1e9f; l_r[r] = 0.f; }
#pragma unroll
  for (int nt = 0; nt < 4; ++nt) oacc[nt] = f32x4{0.f, 0.f, 0.f, 0.f};

  short* pb = &Pbuf[wave][0];

  s16x8 R[8];
  load8(kidx(0, 0), kidx(0, 1), R);

  for (int it = 0; it < 4; ++it) {
    __syncthreads();  // all waves done reading previous KV tiles
#pragma unroll
    for (int bu = 0; bu < 4; ++bu) {
      *(s16x8*)(&KV[bu][sr0 * KSTR + g8 * 8]) = R[2 * bu];
      *(s16x8*)(&KV[bu][sr1 * KSTR + g8 * 8]) = R[2 * bu + 1];
    }
    __syncthreads();  // staging visible to all waves

    load8(kidx(it + 1, 0), kidx(it + 1, 1), R);

    // ---- S0, S1 = Q K^T from LDS ----
    f32x4 s0[4], s1[4];
#pragma unroll
    for (int nt = 0; nt < 4; ++nt) {
      const int fr = (nt * 16 + l15) * KSTR + quad * 8;
      const bfrag ka0 = *(const bfrag*)(&KV[0][fr]);
      const bfrag ka1 = *(const bfrag*)(&KV[0][fr + 32]);
      const bfrag kb0 = *(const bfrag*)(&KV[1][fr]);
      const bfrag kb1 = *(const bfrag*)(&KV[1][fr + 32]);
      s0[nt] = f32x4{0.f,0.f,0.f,0.f}; s1[nt] = f32x4{0.f,0.f,0.f,0.f};
      s0[nt] = MFMA16(qf0, ka0, s0[nt]); s0[nt] = MFMA16(qf1, ka1, s0[nt]);
      s1[nt] = MFMA16(qf0, kb0, s1[nt]); s1[nt] = MFMA16(qf1, kb1, s1[nt]);
    }

    // ---- combined online softmax over 128 keys ----
    float alpha[4];
#pragma unroll
    for (int r = 0; r < 4; ++r) {
      float v = fmaxf(fmaxf(fmaxf(s0[0][r], s0[1][r]), fmaxf(s0[2][r], s0[3][r])),
                      fmaxf(fmaxf(s1[0][r], s1[1][r]), fmaxf(s1[2][r], s1[3][r])));
      v = fmaxf(v, __shfl_xor(v, 1));
      v = fmaxf(v, __shfl_xor(v, 2));
      v = fmaxf(v, __shfl_xor(v, 4));
      v = fmaxf(v, __shfl_xor(v, 8));
      const float mn = fmaxf(m_r[r], v);
      alpha[r] = __expf(m_r[r] - mn);
      m_r[r] = mn;
    }
    float psum[4] = {0.f, 0.f, 0.f, 0.f};
#pragma unroll
    for (int nt = 0; nt < 4; ++nt)
#pragma unroll
      for (int r = 0; r < 4; ++r) {
        const float p0 = __expf(s0[nt][r] - m_r[r]);
        const float p1 = __expf(s1[nt][r] - m_r[r]);
        s0[nt][r] = p0; s1[nt][r] = p1;
        psum[r] += p0 + p1;
      }
#pragma unroll
    for (int r = 0; r < 4; ++r) {
      float v = psum[r];
      v += __shfl_xor(v, 1); v += __shfl_xor(v, 2);
      v += __shfl_xor(v, 4); v += __shfl_xor(v, 8);
      l_r[r] = l_r[r] * alpha[r] + v;
    }

    // ---- P0,P1: C-layout -> A-layout via per-wave LDS ----
#pragma unroll
    for (int nt = 0; nt < 4; ++nt)
#pragma unroll
      for (int r = 0; r < 4; ++r) {
        pb[(quad * 4 + r) * PSTR + nt * 16 + l15]             = f2b(s0[nt][r]);
        pb[16 * PSTR + (quad * 4 + r) * PSTR + nt * 16 + l15] = f2b(s1[nt][r]);
      }

    // ---- O = alpha*O + P0 V0 + P1 V1 (V from LDS) ----
#pragma unroll
    for (int nt = 0; nt < 4; ++nt)
#pragma unroll
      for (int r = 0; r < 4; ++r) oacc[nt][r] *= alpha[r];
#pragma unroll
    for (int s = 0; s < 2; ++s) {
      const bfrag pf0 = *(const bfrag*)(pb + l15 * PSTR + s * 32 + quad * 8);
      const bfrag pf1 = *(const bfrag*)(pb + 16 * PSTR + l15 * PSTR + s * 32 + quad * 8);
#pragma unroll
      for (int nt = 0; nt < 4; ++nt) {
        const int fr = (nt * 16 + l15) * KSTR + s * 32 + quad * 8;
        const bfrag vf0 = *(const bfrag*)(&KV[2][fr]);
        const bfrag vf1 = *(const bfrag*)(&KV[3][fr]);
        oacc[nt] = MFMA16(pf0, vf0, oacc[nt]);
        oacc[nt] = MFMA16(pf1, vf1, oacc[nt]);
      }
    }
  }

  if (!partial) {
    short* op = o + (size_t)(b * SEQ + qb * 64 + wave * 16) * D_MODEL + h * HDIM;
#pragma unroll
    for (int r = 0; r < 4; ++r) {
      const float inv = 1.f / l_r[r];
#pragma unroll
      for (int nt = 0; nt < 4; ++nt)
        op[(size_t)(quad * 4 + r) * D_MODEL + nt * 16 + l15] = f2b(oacc[nt][r] * inv);
    }
  } else {
    const int pi = ((b * NHEAD + h) * 2 + g) * 8 + part;
    short* Op = Opart + (size_t)pi * 4096;
    float* mp = ml + (size_t)pi * 128;
#pragma unroll
    for (int r = 0; r < 4; ++r) {
      const int row = wave * 16 + quad * 4 + r;
#pragma unroll
      for (int nt = 0; nt < 4; ++nt)
        Op[row * 64 + nt * 16 + l15] = f2b(oacc[nt][r]);
      if (l15 == 0) { mp[row] = m_r[r]; mp[64 + row] = l_r[r]; }
    }
  }
}

// ===================== merge partials for global q-blocks =====================
__global__ __launch_bounds__(256) void attn_merge(
    const short* __restrict__ Opart, const float* __restrict__ ml,
    short* __restrict__ o)
{
  const int bi = blockIdx.x;
  const int g = bi & 1, h = (bi >> 1) % NHEAD, b = bi / (2 * NHEAD);
  const int qb = g ? 63 : 0;
  const int pi0 = bi * 8;
#pragma unroll
  for (int e = 0; e < 16; ++e) {
    const int idx = threadIdx.x + e * 256;
    const int r = idx >> 6, c = idx & 63;
    float ms = -1e9f;
#pragma unroll
    for (int p = 0; p < 8; ++p) ms = fmaxf(ms, ml[(size_t)(pi0 + p) * 128 + r]);
    float lsum = 0.f, osum = 0.f;
#pragma unroll
    for (int p = 0; p < 8; ++p) {
      const float w = __expf(ml[(size_t)(pi0 + p) * 128 + r] - ms);
      lsum += w * ml[(size_t)(pi0 + p) * 128 + 64 + r];
      osum += w * b2f(Opart[(size_t)(pi0 + p) * 4096 + idx]);
    }
    o[(size_t)(b * SEQ + qb * 64 + r) * D_MODEL + h * HDIM + c] = f2b(osum / lsum);
  }
}

// ===================== launch =====================
extern "C" void kernel_launch(void* const* d_in, const int* in_sizes, int n_in,
                              void* d_out, int out_size, void* d_ws, size_t ws_size,
                              hipStream_t stream) {
  (void)in_sizes; (void)n_in; (void)out_size; (void)ws_size;
  const float* x    = (const float*)d_in[0];
  const float* ln1s = (const float*)d_in[1];
  const float* ln1b = (const float*)d_in[2];
  const float* Wq   = (const float*)d_in[3];
  const float* Wk   = (const float*)d_in[4];
  const float* Wv   = (const float*)d_in[5];
  const float* Wo   = (const float*)d_in[6];
  const float* ln2s = (const float*)d_in[7];
  const float* ln2b = (const float*)d_in[8];
  const float* W1   = (const float*)d_in[9];
  const float* b1   = (const float*)d_in[10];
  const float* W2   = (const float*)d_in[11];
  const float* b2   = (const float*)d_in[12];
  float* out = (float*)d_out;

  // ws layout (~77.1 MiB): weightsT (14.2) | hbuf (12.6) | BIG 4x12.6 (tbuf)
  short* WqT  = (short*)((char*)d_ws + 256);
  short* WkT  = WqT  + 768 * 768;          // WqT|WkT|WvT contiguous => fused QKV Bt[2304][768]
  short* WvT  = WkT  + 768 * 768;
  short* WoT  = WvT  + 768 * 768;
  short* W1T  = WoT  + 768 * 768;          // (3072,768)
  short* W2T  = W1T  + (size_t)3072 * 768; // (768,3072)
  short* hbuf = W2T  + (size_t)3072 * 768;
  short* qbuf = hbuf + (size_t)ROWS * D_MODEL;
  short* kbuf = qbuf + (size_t)ROWS * D_MODEL;
  short* vtb  = kbuf + (size_t)ROWS * D_MODEL;
  short* obuf = vtb  + (size_t)ROWS * D_MODEL;
  short* tbuf = qbuf;   // MLP intermediate spans qbuf..obuf (4*ROWS*D_MODEL == ROWS*DFF)
  // attention partials in hbuf (dead between QKV GEMM and ln2): 3.3 MB
  short* Opart = hbuf;
  float* mlbuf = (float*)(hbuf + (size_t)384 * 4096);

  TrArgs ta;
  ta.src[0] = Wq; ta.src[1] = Wk; ta.src[2] = Wv; ta.src[3] = Wo; ta.src[4] = W1; ta.src[5] = W2;
  ta.dst[0] = WqT; ta.dst[1] = WkT; ta.dst[2] = WvT; ta.dst[3] = WoT; ta.dst[4] = W1T; ta.dst[5] = W2T;

  // merged pre-pass: weight transposes (6912 blocks) + ln1 (8192 blocks)
  pre_kernel<<<6912 + ROWS, 256, 0, stream>>>(ta, x, ln1s, ln1b, hbuf);

  // QKV: M=8192, N=2304, K=768
  gemm_bt<M_QKV, 128><<<dim3(64, 18), 256, 0, stream>>>(hbuf, WqT, qbuf, kbuf, vtb, nullptr, nullptr, 2304, 768);

  attn_kernel<<<dim3(78, 12, 2), 256, 0, stream>>>(qbuf, kbuf, vtb, obuf, Opart, mlbuf);
  attn_merge<<<48, 256, 0, stream>>>(Opart, mlbuf, obuf);

  // attn out-proj + residual: M=8192, N=768, K=768 -> out = proj + x  (x1)
  gemm_bt<M_RES, 64><<<dim3(64, 12), 256, 0, stream>>>(obuf, WoT, out, nullptr, nullptr, x, nullptr, 768, 768);

  ln_kernel<<<ROWS, 256, 0, stream>>>(out, ln2s, ln2b, hbuf);

  // MLP1: M=8192, N=3072, K=768
  gemm_bt<M_BRELU, 128><<<dim3(64, 24), 256, 0, stream>>>(hbuf, W1T, tbuf, nullptr, nullptr, nullptr, b1, 3072, 768);
  // MLP2: M=8192, N=768, K=3072
  gemm_bt<M_BRES, 64> <<<dim3(64, 12), 256, 0, stream>>>(tbuf, W2T, out, nullptr, nullptr, out, b2, 768, 3072);
}